// Round 13
// baseline (179.143 us; speedup 1.0000x reference)
//
#include <hip/hip_runtime.h>

#define N_ROWS 8192
#define NX     4096
#define DIM    512
#define BT     128          // block tile (rows & cols)
#define NT     64           // N_ROWS / BT tiles per side
#define NTRI   2080         // NT*(NT+1)/2 upper-triangle tiles
#define BK     32           // K elements per stage (64 B per row)
#define NPERS  768          // persistent blocks: exactly 3 per CU

typedef __bf16 bf16_t;
typedef bf16_t bf16x8 __attribute__((ext_vector_type(8)));
typedef float  f32x4  __attribute__((ext_vector_type(4)));

#if __has_builtin(__builtin_amdgcn_exp2f)
  #define EXP2F __builtin_amdgcn_exp2f
#else
  #define EXP2F exp2f
#endif

// ws layout (bytes):
//   0       sqrow[8192]  float   (32768 B)
//   32768   colsum[512]  float   ( 2048 B)
//   34816   cvals[5]     float   (   20 B)  cvals[k] = -log2e/(bw*mult_k)
//   34840   tk1          uint    colsum ticket
//   34844   tk2          uint    final ticket
//   34848   S1acc        double  sum of sqrow
//   34856   wq           uint    dynamic tile queue head (init NPERS)
//   34860   flag         uint    cvals-ready flag
//   34944   acc[8*16]    double  8 slots, 128 B apart
//   36864   Zh[8192*512] bf16    bf16 copy of concat(X,Y)
//
// NO __threadfence anywhere (R7/R8 A/B: per-block L2 writeback doubled
// k_pair's stage latency chip-wide). All cross-block data moves via
// device-scope atomics; ordering = returning atomic -> asm sink ->
// s_waitcnt vmcnt(0) -> flag/ticket atomic.

__device__ __forceinline__ const float* zrow(const float* X, const float* Y, int r) {
    return (r < NX) ? (X + (size_t)r * DIM) : (Y + (size_t)(r - NX) * DIM);
}

__device__ __forceinline__ void gload_lds16(const bf16_t* g, bf16_t* l) {
    __builtin_amdgcn_global_load_lds(
        (__attribute__((address_space(1))) void*)(void*)(g),
        (__attribute__((address_space(3))) void*)(void*)(l), 16, 0, 0);
}

// supertile-blocked triangular decode (8x8-tile supertiles; 8 diag x 36 +
// 28 off-diag x 64 = 2080) with XCD interleave spread
__device__ __forceinline__ void decode_tile(int T, int* pti, int* ptj) {
    int q = (T & 7) * (NTRI / 8) + (T >> 3);
    int I = 0, rem = q;
    #pragma unroll
    for (int it = 0; it < 8; ++it) {
        int rowcnt = 36 + (7 - I) * 64;
        if (rem >= rowcnt && I < 7) { rem -= rowcnt; ++I; } else break;
    }
    if (rem < 36) {
        int a = 0;
        #pragma unroll
        for (int it = 0; it < 7; ++it) {
            int nxt = (a + 1) * 8 - (a + 1) * a / 2;
            if (nxt <= rem) ++a; else break;
        }
        int off = a * 8 - a * (a - 1) / 2;
        *pti = I * 8 + a;
        *ptj = I * 8 + a + (rem - off);
    } else {
        int r2 = rem - 36;
        int J = I + 1 + (r2 >> 6);
        int w = r2 & 63;
        *pti = I * 8 + (w >> 3);
        *ptj = J * 8 + (w & 7);
    }
}

// fused: bf16 copy + exact fp32 row norms + zero-init of all control state.
__global__ void k_prep(const float* __restrict__ X, const float* __restrict__ Y,
                       bf16_t* __restrict__ Zh, float* __restrict__ sqrow,
                       float* __restrict__ colsum, unsigned* __restrict__ tk1,
                       unsigned* __restrict__ tk2, double* __restrict__ S1acc,
                       unsigned* __restrict__ wq, unsigned* __restrict__ flag) {
    int t = threadIdx.x;
    if (blockIdx.x == 0) {
        colsum[t] = 0.f; colsum[t + 256] = 0.f;
        if (t == 0) { *tk1 = 0u; *tk2 = 0u; *S1acc = 0.0; *wq = NPERS; *flag = 0u; }
    }
    int wv = t >> 6, lane = t & 63;
    int row = blockIdx.x * 4 + wv;
    const float4* z4 = (const float4*)zrow(X, Y, row);
    float4 a = z4[lane * 2], b = z4[lane * 2 + 1];
    bf16x8 h;
    h[0] = (bf16_t)a.x; h[1] = (bf16_t)a.y; h[2] = (bf16_t)a.z; h[3] = (bf16_t)a.w;
    h[4] = (bf16_t)b.x; h[5] = (bf16_t)b.y; h[6] = (bf16_t)b.z; h[7] = (bf16_t)b.w;
    *(bf16x8*)(Zh + (size_t)row * DIM + lane * 8) = h;
    float s = a.x*a.x + a.y*a.y + a.z*a.z + a.w*a.w
            + b.x*b.x + b.y*b.y + b.z*b.z + b.w*b.w;
    #pragma unroll
    for (int off = 32; off > 0; off >>= 1) s += __shfl_down(s, off);
    if (lane == 0) sqrow[row] = s;
}

// PERSISTENT fused k_pair: 768 blocks (3/CU, all co-resident).
// Blocks 0..127 first run a colsum slab (16 col-groups x 8 row-slabs;
// g==0 blocks also reduce S1); the 128th ticket computes bw -> cvals
// (atomicExch), zeroes acc, then sets flag (after vmcnt(0) completion
// order). Then ALL blocks run the proven R11 K-loop on tiles from a
// dynamic queue (initial tile = blockIdx; next grabbed one tile ahead in
// the tile preamble so the cross-tile stage prefetch at steps 14/15
// still flows). Epilogue one-shot-spins on flag (set @~4us, first
// epilogue @~20us -> never iterates; all blocks co-resident => safe),
// reads c4 via device-scope atomic. Fence-free final ticket -> out.
__global__ __launch_bounds__(256, 3) void k_pair(const bf16_t* __restrict__ Zh,
                                                 const float* __restrict__ sqrow,
                                                 float* __restrict__ colsum,
                                                 float* __restrict__ cvals,
                                                 double* __restrict__ S1acc,
                                                 unsigned* __restrict__ tk1,
                                                 unsigned* __restrict__ wq,
                                                 unsigned* __restrict__ flag,
                                                 double* __restrict__ acc,
                                                 unsigned* __restrict__ tk2,
                                                 float* __restrict__ out) {
    int b = blockIdx.x;
    __shared__ bf16_t As[3][4096];   // 3 x 8 KB stage buffers (48 KB total)
    __shared__ bf16_t Bs[3][4096];
    __shared__ float wsum[4];
    __shared__ int   lds_next;
    __shared__ float lds_c4;

    int t = threadIdx.x, lane = t & 63, wv = t >> 6;
    int n16 = lane & 15, q16 = lane >> 4;

    // ---- phase A: colsum + S1 + bw (blocks 0..127; LDS reused pre-staging)
    if (b < 128) {
        float* red = (float*)&Bs[0][0];        // [4][4][8] floats
        double* dred = (double*)&As[0][0];     // [256] doubles
        int g = b & 15, slab = b >> 4;
        int c0 = g * 32 + q16 * 8;
        float s[8] = {0.f,0.f,0.f,0.f,0.f,0.f,0.f,0.f};
        for (int it = 0; it < 16; ++it) {
            int r = slab * 1024 + it * 64 + wv * 16 + n16;
            bf16x8 v = *(const bf16x8*)(Zh + (size_t)r * DIM + c0);
            #pragma unroll
            for (int j = 0; j < 8; ++j) s[j] += (float)v[j];
        }
        #pragma unroll
        for (int off = 8; off >= 1; off >>= 1)
            #pragma unroll
            for (int j = 0; j < 8; ++j) s[j] += __shfl_down(s[j], off);
        if (n16 == 0)
            #pragma unroll
            for (int j = 0; j < 8; ++j) red[(wv * 4 + q16) * 8 + j] = s[j];
        __syncthreads();
        float oldc = 0.f;
        if (t < 32) {
            int q = t >> 3, j = t & 7;
            float v = 0.f;
            #pragma unroll
            for (int w = 0; w < 4; ++w) v += red[(w * 4 + q) * 8 + j];
            oldc = atomicAdd(&colsum[g * 32 + q * 8 + j], v);
        }
        double olds = 0.0;
        if (g == 0) {   // S1 over this slab's 1024 rows
            int i = slab * 1024 + t;
            double d = (double)sqrow[i] + (double)sqrow[i + 256]
                     + (double)sqrow[i + 512] + (double)sqrow[i + 768];
            #pragma unroll
            for (int off = 32; off > 0; off >>= 1) d += __shfl_down(d, off);
            if (lane == 0) olds = atomicAdd(S1acc, d);
        }
        asm volatile("" :: "v"(oldc), "v"(olds));
        asm volatile("s_waitcnt vmcnt(0)" ::: "memory");   // atomics complete
        __syncthreads();
        __shared__ int is_last;
        if (t == 0) is_last = (atomicAdd(tk1, 1u) == 127u);
        __syncthreads();
        if (is_last) {
            float cv0 = atomicAdd(&colsum[t], 0.f);
            float cv1 = atomicAdd(&colsum[t + 256], 0.f);
            dred[t] = (double)cv0 * cv0 + (double)cv1 * cv1;
            __syncthreads();
            for (int off = 128; off > 0; off >>= 1) {
                if (t < off) dred[t] += dred[t + off];
                __syncthreads();
            }
            if (t < 8) {
                unsigned long long o =
                    atomicExch((unsigned long long*)&acc[t * 16], 0ull);
                asm volatile("" :: "v"(o));
            }
            if (t == 0) {
                double S1 = atomicAdd(S1acc, 0.0);
                double n = (double)N_ROWS;
                double bw = (2.0 * n * S1 - 2.0 * dred[0]) / (n * n - n);
                const double LOG2E = 1.4426950408889634;
                double mult = 0.25;
                float olda = 0.f;
                for (int k = 0; k < 5; ++k) {
                    olda += atomicExch(&cvals[k], (float)(-LOG2E / (bw * mult)));
                    mult *= 2.0;
                }
                asm volatile("" :: "v"(olda));
                asm volatile("s_waitcnt vmcnt(0)" ::: "memory"); // cvals+acc done
                unsigned of = atomicExch(flag, 1u);
                asm volatile("" :: "v"(of));
            }
            __syncthreads();
        }
    }

    // ---- phase B: persistent tile loop (R11-verified body + dynamic queue)
    int r0_, q0_, r1_, q1_;
    { int c0 = t;       r0_ = c0 >> 2; q0_ = (c0 & 3) ^ ((r0_ >> 1) & 3);
      int c1 = 256 + t; r1_ = c1 >> 2; q1_ = (c1 & 3) ^ ((r1_ >> 1) & 3); }
    int ldsoff0 = (wv * 64) * 8;
    int ldsoff1 = (256 + wv * 64) * 8;
    int wr = wv >> 1, wc = wv & 1;
    int aoff[4], boff[4];
    #pragma unroll
    for (int aa = 0; aa < 4; ++aa) {
        int r = 16 * (wr * 4 + aa) + n16;
        aoff[aa] = (r * 4 + (q16 ^ ((r >> 1) & 3))) * 8;
    }
    #pragma unroll
    for (int bb = 0; bb < 4; ++bb) {
        int r = 16 * (wc * 4 + bb) + n16;
        boff[bb] = (r * 4 + (q16 ^ ((r >> 1) & 3))) * 8;
    }

#define SETPTRS(TI, TJ, A0, B0, A1, B1) do {                        \
        (A0) = Zh + (size_t)((TI) * BT + r0_) * DIM + q0_ * 8;      \
        (B0) = Zh + (size_t)((TJ) * BT + r0_) * DIM + q0_ * 8;      \
        (A1) = Zh + (size_t)((TI) * BT + r1_) * DIM + q1_ * 8;      \
        (B1) = Zh + (size_t)((TJ) * BT + r1_) * DIM + q1_ * 8;      \
    } while (0)
#define STAGEP(A0, B0, A1, B1, KN, BUF) do {                        \
        gload_lds16((A0) + (KN), &As[BUF][ldsoff0]);                \
        gload_lds16((B0) + (KN), &Bs[BUF][ldsoff0]);                \
        gload_lds16((A1) + (KN), &As[BUF][ldsoff1]);                \
        gload_lds16((B1) + (KN), &Bs[BUF][ldsoff1]);                \
    } while (0)
#define WAITBAR(VM) do {                                            \
        asm volatile("s_waitcnt vmcnt(" VM ")" ::: "memory");       \
        __builtin_amdgcn_s_barrier();                               \
        __builtin_amdgcn_sched_barrier(0);                          \
    } while (0)
#define DOMFMA(RB) do {                                             \
        const bf16_t* Ab = &As[RB][0];                              \
        const bf16_t* Bb = &Bs[RB][0];                              \
        bf16x8 av[4], bv[4];                                        \
        _Pragma("unroll")                                           \
        for (int aa = 0; aa < 4; ++aa) av[aa] = *(const bf16x8*)(Ab + aoff[aa]); \
        _Pragma("unroll")                                           \
        for (int bb = 0; bb < 4; ++bb) bv[bb] = *(const bf16x8*)(Bb + boff[bb]); \
        __builtin_amdgcn_s_setprio(1);                              \
        _Pragma("unroll")                                           \
        for (int aa = 0; aa < 4; ++aa)                              \
            _Pragma("unroll")                                       \
            for (int bb = 0; bb < 4; ++bb)                          \
                accf[aa][bb] = __builtin_amdgcn_mfma_f32_16x16x32_bf16( \
                    av[aa], bv[bb], accf[aa][bb], 0, 0, 0);         \
        __builtin_amdgcn_s_setprio(0);                              \
    } while (0)

    int ti, tj;
    decode_tile(b, &ti, &tj);
    const bf16_t *cA0, *cB0, *cA1, *cB1;
    SETPTRS(ti, tj, cA0, cB0, cA1, cB1);
    STAGEP(cA0, cB0, cA1, cB1, 0, 0);        // tile stage0 -> buf0
    STAGEP(cA0, cB0, cA1, cB1, BK, 1);       // tile stage1 -> buf1

    int g3 = 0;          // buffer rotation base = tile counter mod 3
    float c4 = 0.f;
    int seen = 0;

    for (;;) {
        // preamble: grab next tile id (needed only at steps 14/15)
        if (t == 0) lds_next = (int)atomicAdd(wq, 1u);
        __syncthreads();   // implicit drain: stages 0/1 issued >=1 step ago
        int nxt = lds_next;
        int has_next = (nxt < NTRI);
        int nti = 0, ntj = 0;
        if (has_next) decode_tile(nxt, &nti, &ntj);
        const bf16_t *nA0 = cA0, *nB0 = cB0, *nA1 = cA1, *nB1 = cB1;
        if (has_next) SETPTRS(nti, ntj, nA0, nB0, nA1, nB1);

        f32x4 accf[4][4];
        #pragma unroll
        for (int a = 0; a < 4; ++a)
            #pragma unroll
            for (int bb = 0; bb < 4; ++bb)
                accf[a][bb] = (f32x4){0.f, 0.f, 0.f, 0.f};

        int rb = g3;
        const bf16_t *pA0 = cA0 + 2 * BK, *pB0 = cB0 + 2 * BK;
        const bf16_t *pA1 = cA1 + 2 * BK, *pB1 = cB1 + 2 * BK;
        for (int s = 0; s < 14; ++s) {
            WAITBAR("4");
            int wb = rb + 2; if (wb >= 3) wb -= 3;
            STAGEP(pA0, pB0, pA1, pB1, 0, wb);
            pA0 += BK; pB0 += BK; pA1 += BK; pB1 += BK;
            DOMFMA(rb);
            ++rb; if (rb == 3) rb = 0;
        }
        {   // step 14: read (g3+2)%3; stage next tile's stage0 -> (g3+1)%3
            WAITBAR("4");
            int b1 = g3 + 1; if (b1 >= 3) b1 -= 3;
            if (has_next) STAGEP(nA0, nB0, nA1, nB1, 0, b1);
            int b2 = g3 + 2; if (b2 >= 3) b2 -= 3;
            DOMFMA(b2);
        }
        {   // step 15: read g3; stage next tile's stage1 -> (g3+2)%3
            if (has_next) {
                WAITBAR("4");
                int b2 = g3 + 2; if (b2 >= 3) b2 -= 3;
                STAGEP(nA0, nB0, nA1, nB1, BK, b2);
            } else {
                WAITBAR("0");
            }
            DOMFMA(g3);
        }

        // epilogue: one-shot cvals sync, then 5-bandwidth RBF squaring chain
        if (!seen) {
            if (t == 0) {
                while (atomicAdd(flag, 0u) == 0u) __builtin_amdgcn_s_sleep(8);
                lds_c4 = atomicAdd(&cvals[4], 0.f);
            }
            __syncthreads();
            c4 = lds_c4;
            seen = 1;
        }
        int i0 = ti * BT + wr * 64;
        int j0 = tj * BT + wc * 64;
        float sqi[4][4], sqj[4];
        #pragma unroll
        for (int aa = 0; aa < 4; ++aa)
            #pragma unroll
            for (int r = 0; r < 4; ++r)
                sqi[aa][r] = sqrow[i0 + 16 * aa + q16 * 4 + r];
        #pragma unroll
        for (int bb = 0; bb < 4; ++bb)
            sqj[bb] = sqrow[j0 + 16 * bb + n16];

        float s_local = 0.f;
        #pragma unroll
        for (int aa = 0; aa < 4; ++aa) {
            #pragma unroll
            for (int bb = 0; bb < 4; ++bb) {
                #pragma unroll
                for (int r = 0; r < 4; ++r) {
                    float d2 = fmaf(-2.f, accf[aa][bb][r], sqi[aa][r] + sqj[bb]);
                    d2 = fmaxf(d2, 0.f);
                    float e4 = EXP2F(d2 * c4);
                    float e3 = e4 * e4;
                    float e2 = e3 * e3;
                    float e1 = e2 * e2;
                    float e0 = e1 * e1;
                    s_local += e4 + e3 + e2 + e1 + e0;
                }
            }
        }
        #pragma unroll
        for (int off = 32; off > 0; off >>= 1) s_local += __shfl_down(s_local, off);
        if (lane == 0) wsum[wv] = s_local;
        __syncthreads();   // prefetched next-tile stages long done by now
        if (t == 0) {
            float bs = wsum[0] + wsum[1] + wsum[2] + wsum[3];
            double si = (ti < NT / 2) ? 1.0 : -1.0;
            double sj = (tj < NT / 2) ? 1.0 : -1.0;
            double w = si * sj * ((ti == tj) ? 1.0 : 2.0);
            double oldv = atomicAdd(&acc[(b & 7) * 16], w * (double)bs);
            asm volatile("" :: "v"(oldv));
        }
        if (!has_next) break;
        ti = nti; tj = ntj;
        cA0 = nA0; cB0 = nB0; cA1 = nA1; cB1 = nB1;
        ++g3; if (g3 == 3) g3 = 0;
    }

    // fence-free final ticket (all older VMEM incl. acc atomics retired)
    if (t == 0) {
        asm volatile("s_waitcnt vmcnt(0)" ::: "memory");
        unsigned old = atomicAdd(tk2, 1u);
        if (old == NPERS - 1) {
            double ssum = 0.0;
            #pragma unroll
            for (int i = 0; i < 8; ++i) ssum += atomicAdd(&acc[i * 16], 0.0);
            out[0] = (float)(ssum / ((double)NX * (double)NX));
        }
    }
#undef SETPTRS
#undef STAGEP
#undef WAITBAR
#undef DOMFMA
}

extern "C" void kernel_launch(void* const* d_in, const int* in_sizes, int n_in,
                              void* d_out, int out_size, void* d_ws, size_t ws_size,
                              hipStream_t stream) {
    const float* X = (const float*)d_in[0];
    const float* Y = (const float*)d_in[1];
    float* out = (float*)d_out;

    float*    sqrow  = (float*)d_ws;
    float*    colsum = sqrow + 8192;
    float*    cvals  = (float*)((char*)d_ws + 34816);
    unsigned* tk1    = (unsigned*)((char*)d_ws + 34840);
    unsigned* tk2    = (unsigned*)((char*)d_ws + 34844);
    double*   S1acc  = (double*)((char*)d_ws + 34848);
    unsigned* wq     = (unsigned*)((char*)d_ws + 34856);
    unsigned* flag   = (unsigned*)((char*)d_ws + 34860);
    double*   acc    = (double*)((char*)d_ws + 34944);
    bf16_t*   Zh     = (bf16_t*)((char*)d_ws + 36864);

    k_prep<<<2048, 256, 0, stream>>>(X, Y, Zh, sqrow, colsum, tk1, tk2, S1acc, wq, flag);
    k_pair<<<NPERS, 256, 0, stream>>>(Zh, sqrow, colsum, cvals, S1acc, tk1, wq, flag,
                                      acc, tk2, out);
}

// Round 14
// 136.858 us; speedup vs baseline: 1.3090x; 1.3090x over previous
//
#include <hip/hip_runtime.h>

#define N_ROWS 8192
#define NX     4096
#define DIM    512
#define BT     128          // block tile (rows & cols)
#define NT     64           // N_ROWS / BT tiles per side
#define NTRI   2080         // NT*(NT+1)/2 upper-triangle tiles
#define BK     32           // K elements per stage (64 B per row)
#define NPERS  768          // persistent blocks: exactly 3 per CU
#define CSBASE 640          // colsum duty: blocks 640..767 (the 2-tile blocks)

typedef __bf16 bf16_t;
typedef bf16_t bf16x8 __attribute__((ext_vector_type(8)));
typedef float  f32x4  __attribute__((ext_vector_type(4)));

#if __has_builtin(__builtin_amdgcn_exp2f)
  #define EXP2F __builtin_amdgcn_exp2f
#else
  #define EXP2F exp2f
#endif

// ws layout (bytes):
//   0       sqrow[8192]  float
//   32768   colsum[512]  float
//   34816   cvals[5]     float   cvals[k] = -log2e/(bw*mult_k)
//   34840   tk1          uint    colsum ticket
//   34844   tk2          uint    final ticket
//   34848   S1acc        double  sum of sqrow
//   34860   flag         uint    cvals-ready flag
//   34944   acc[8*16]    double  8 slots, 128 B apart
//   36864   Zh[8192*512] bf16
//
// NO __threadfence anywhere (R7/R8 A/B: per-block L2 writeback doubled
// k_pair stage latency chip-wide). Cross-block ordering = returning
// atomic -> asm sink -> s_waitcnt vmcnt(0) -> flag/ticket atomic.
// STATIC tile assignment (b, b+768, b+1536) keeps tile chunk T&7 == b&7
// == XCD id: R12's dynamic queue broke this and FETCH went 22->71 MB
// with k_pair 63->119 us.

__device__ __forceinline__ const float* zrow(const float* X, const float* Y, int r) {
    return (r < NX) ? (X + (size_t)r * DIM) : (Y + (size_t)(r - NX) * DIM);
}

__device__ __forceinline__ void gload_lds16(const bf16_t* g, bf16_t* l) {
    __builtin_amdgcn_global_load_lds(
        (__attribute__((address_space(1))) void*)(void*)(g),
        (__attribute__((address_space(3))) void*)(void*)(l), 16, 0, 0);
}

// supertile-blocked triangular decode (8x8-tile supertiles) + XCD spread
__device__ __forceinline__ void decode_tile(int T, int* pti, int* ptj) {
    int q = (T & 7) * (NTRI / 8) + (T >> 3);
    int I = 0, rem = q;
    #pragma unroll
    for (int it = 0; it < 8; ++it) {
        int rowcnt = 36 + (7 - I) * 64;
        if (rem >= rowcnt && I < 7) { rem -= rowcnt; ++I; } else break;
    }
    if (rem < 36) {
        int a = 0;
        #pragma unroll
        for (int it = 0; it < 7; ++it) {
            int nxt = (a + 1) * 8 - (a + 1) * a / 2;
            if (nxt <= rem) ++a; else break;
        }
        int off = a * 8 - a * (a - 1) / 2;
        *pti = I * 8 + a;
        *ptj = I * 8 + a + (rem - off);
    } else {
        int r2 = rem - 36;
        int J = I + 1 + (r2 >> 6);
        int w = r2 & 63;
        *pti = I * 8 + (w >> 3);
        *ptj = J * 8 + (w & 7);
    }
}

// fused: bf16 copy + exact fp32 row norms + zero-init of control state.
__global__ void k_prep(const float* __restrict__ X, const float* __restrict__ Y,
                       bf16_t* __restrict__ Zh, float* __restrict__ sqrow,
                       float* __restrict__ colsum, unsigned* __restrict__ tk1,
                       unsigned* __restrict__ tk2, double* __restrict__ S1acc,
                       unsigned* __restrict__ flag) {
    int t = threadIdx.x;
    if (blockIdx.x == 0) {
        colsum[t] = 0.f; colsum[t + 256] = 0.f;
        if (t == 0) { *tk1 = 0u; *tk2 = 0u; *S1acc = 0.0; *flag = 0u; }
    }
    int wv = t >> 6, lane = t & 63;
    int row = blockIdx.x * 4 + wv;
    const float4* z4 = (const float4*)zrow(X, Y, row);
    float4 a = z4[lane * 2], b = z4[lane * 2 + 1];
    bf16x8 h;
    h[0] = (bf16_t)a.x; h[1] = (bf16_t)a.y; h[2] = (bf16_t)a.z; h[3] = (bf16_t)a.w;
    h[4] = (bf16_t)b.x; h[5] = (bf16_t)b.y; h[6] = (bf16_t)b.z; h[7] = (bf16_t)b.w;
    *(bf16x8*)(Zh + (size_t)row * DIM + lane * 8) = h;
    float s = a.x*a.x + a.y*a.y + a.z*a.z + a.w*a.w
            + b.x*b.x + b.y*b.y + b.z*b.z + b.w*b.w;
    #pragma unroll
    for (int off = 32; off > 0; off >>= 1) s += __shfl_down(s, off);
    if (lane == 0) sqrow[row] = s;
}

// PERSISTENT fused k_pair: 768 blocks (3/CU, all co-resident).
// Blocks 640..767 (the 2-tile blocks: b>=544 have only 2 static tiles)
// first run a colsum slab (16 col-groups x 8 row-slabs; g==0 blocks also
// reduce S1); the 128th ticket computes bw -> cvals (atomicExch), zeroes
// acc, sets flag (after vmcnt(0) completion order). The colsum cost fills
// those blocks' load-imbalance slack instead of adding to the makespan.
// All blocks then run the R11-verified static 3-tile K-loop: 3 stage
// buffers / 48 KB, one raw s_barrier per K-step, counted vmcnt(4), T5
// setprio, cross-tile stage prefetch at steps 14/15 (rotation (g+s)%3),
// m89/m91-verified layouts, global-side XOR swizzle. Epilogue one-shot
// spins on flag (set @~8us, first epilogue @~21us -> never iterates; all
// blocks co-resident => progress guaranteed). Fence-free final ticket.
__global__ __launch_bounds__(256, 3) void k_pair(const bf16_t* __restrict__ Zh,
                                                 const float* __restrict__ sqrow,
                                                 float* __restrict__ colsum,
                                                 float* __restrict__ cvals,
                                                 double* __restrict__ S1acc,
                                                 unsigned* __restrict__ tk1,
                                                 unsigned* __restrict__ flag,
                                                 double* __restrict__ acc,
                                                 unsigned* __restrict__ tk2,
                                                 float* __restrict__ out) {
    int b = blockIdx.x;
    __shared__ bf16_t As[3][4096];   // 3 x 8 KB stage buffers (48 KB total)
    __shared__ bf16_t Bs[3][4096];
    __shared__ float wsum[4];
    __shared__ float lds_c4;

    int t = threadIdx.x, lane = t & 63, wv = t >> 6;
    int n16 = lane & 15, q16 = lane >> 4;

    // ---- phase A: colsum + S1 + bw on blocks 640..767 (LDS as scratch)
    if (b >= CSBASE) {
        float* red = (float*)&Bs[0][0];        // [4][4][8] floats
        double* dred = (double*)&As[0][0];     // [256] doubles
        int cb = b - CSBASE;
        int g = cb & 15, slab = cb >> 4;
        int c0 = g * 32 + q16 * 8;
        float s[8] = {0.f,0.f,0.f,0.f,0.f,0.f,0.f,0.f};
        for (int it = 0; it < 16; ++it) {
            int r = slab * 1024 + it * 64 + wv * 16 + n16;
            bf16x8 v = *(const bf16x8*)(Zh + (size_t)r * DIM + c0);
            #pragma unroll
            for (int j = 0; j < 8; ++j) s[j] += (float)v[j];
        }
        #pragma unroll
        for (int off = 8; off >= 1; off >>= 1)
            #pragma unroll
            for (int j = 0; j < 8; ++j) s[j] += __shfl_down(s[j], off);
        if (n16 == 0)
            #pragma unroll
            for (int j = 0; j < 8; ++j) red[(wv * 4 + q16) * 8 + j] = s[j];
        __syncthreads();
        float oldc = 0.f;
        if (t < 32) {
            int q = t >> 3, j = t & 7;
            float v = 0.f;
            #pragma unroll
            for (int w = 0; w < 4; ++w) v += red[(w * 4 + q) * 8 + j];
            oldc = atomicAdd(&colsum[g * 32 + q * 8 + j], v);
        }
        double olds = 0.0;
        if (g == 0) {   // S1 over this slab's 1024 rows
            int i = slab * 1024 + t;
            double d = (double)sqrow[i] + (double)sqrow[i + 256]
                     + (double)sqrow[i + 512] + (double)sqrow[i + 768];
            #pragma unroll
            for (int off = 32; off > 0; off >>= 1) d += __shfl_down(d, off);
            if (lane == 0) olds = atomicAdd(S1acc, d);
        }
        asm volatile("" :: "v"(oldc), "v"(olds));
        asm volatile("s_waitcnt vmcnt(0)" ::: "memory");   // atomics complete
        __syncthreads();
        __shared__ int is_last;
        if (t == 0) is_last = (atomicAdd(tk1, 1u) == 127u);
        __syncthreads();
        if (is_last) {
            float cv0 = atomicAdd(&colsum[t], 0.f);
            float cv1 = atomicAdd(&colsum[t + 256], 0.f);
            dred[t] = (double)cv0 * cv0 + (double)cv1 * cv1;
            __syncthreads();
            for (int off = 128; off > 0; off >>= 1) {
                if (t < off) dred[t] += dred[t + off];
                __syncthreads();
            }
            if (t < 8) {
                unsigned long long o =
                    atomicExch((unsigned long long*)&acc[t * 16], 0ull);
                asm volatile("" :: "v"(o));
            }
            if (t == 0) {
                double S1 = atomicAdd(S1acc, 0.0);
                double n = (double)N_ROWS;
                double bw = (2.0 * n * S1 - 2.0 * dred[0]) / (n * n - n);
                const double LOG2E = 1.4426950408889634;
                double mult = 0.25;
                float olda = 0.f;
                for (int k = 0; k < 5; ++k) {
                    olda += atomicExch(&cvals[k], (float)(-LOG2E / (bw * mult)));
                    mult *= 2.0;
                }
                asm volatile("" :: "v"(olda));
                asm volatile("s_waitcnt vmcnt(0)" ::: "memory");
                unsigned of = atomicExch(flag, 1u);
                asm volatile("" :: "v"(of));
            }
            __syncthreads();
        }
    }

    // ---- phase B: R11-verified static persistent tile loop
    int ntile = (b < NTRI - 2 * NPERS) ? 3 : 2;   // b<544: 3 tiles, else 2
    int tis[3], tjs[3];
    #pragma unroll
    for (int g = 0; g < 3; ++g) {
        int T = b + g * NPERS;
        int ti_ = 0, tj_ = 0;
        if (T < NTRI) decode_tile(T, &ti_, &tj_);
        tis[g] = ti_; tjs[g] = tj_;
    }

    int r0_, q0_, r1_, q1_;
    { int c0 = t;       r0_ = c0 >> 2; q0_ = (c0 & 3) ^ ((r0_ >> 1) & 3);
      int c1 = 256 + t; r1_ = c1 >> 2; q1_ = (c1 & 3) ^ ((r1_ >> 1) & 3); }
    int ldsoff0 = (wv * 64) * 8;
    int ldsoff1 = (256 + wv * 64) * 8;
    int wr = wv >> 1, wc = wv & 1;
    int aoff[4], boff[4];
    #pragma unroll
    for (int aa = 0; aa < 4; ++aa) {
        int r = 16 * (wr * 4 + aa) + n16;
        aoff[aa] = (r * 4 + (q16 ^ ((r >> 1) & 3))) * 8;
    }
    #pragma unroll
    for (int bb = 0; bb < 4; ++bb) {
        int r = 16 * (wc * 4 + bb) + n16;
        boff[bb] = (r * 4 + (q16 ^ ((r >> 1) & 3))) * 8;
    }

#define SETPTRS(TI, TJ, A0, B0, A1, B1) do {                        \
        (A0) = Zh + (size_t)((TI) * BT + r0_) * DIM + q0_ * 8;      \
        (B0) = Zh + (size_t)((TJ) * BT + r0_) * DIM + q0_ * 8;      \
        (A1) = Zh + (size_t)((TI) * BT + r1_) * DIM + q1_ * 8;      \
        (B1) = Zh + (size_t)((TJ) * BT + r1_) * DIM + q1_ * 8;      \
    } while (0)
#define STAGEP(A0, B0, A1, B1, KN, BUF) do {                        \
        gload_lds16((A0) + (KN), &As[BUF][ldsoff0]);                \
        gload_lds16((B0) + (KN), &Bs[BUF][ldsoff0]);                \
        gload_lds16((A1) + (KN), &As[BUF][ldsoff1]);                \
        gload_lds16((B1) + (KN), &Bs[BUF][ldsoff1]);                \
    } while (0)
#define WAITBAR(VM) do {                                            \
        asm volatile("s_waitcnt vmcnt(" VM ")" ::: "memory");       \
        __builtin_amdgcn_s_barrier();                               \
        __builtin_amdgcn_sched_barrier(0);                          \
    } while (0)
#define DOMFMA(RB) do {                                             \
        const bf16_t* Ab = &As[RB][0];                              \
        const bf16_t* Bb = &Bs[RB][0];                              \
        bf16x8 av[4], bv[4];                                        \
        _Pragma("unroll")                                           \
        for (int aa = 0; aa < 4; ++aa) av[aa] = *(const bf16x8*)(Ab + aoff[aa]); \
        _Pragma("unroll")                                           \
        for (int bb = 0; bb < 4; ++bb) bv[bb] = *(const bf16x8*)(Bb + boff[bb]); \
        __builtin_amdgcn_s_setprio(1);                              \
        _Pragma("unroll")                                           \
        for (int aa = 0; aa < 4; ++aa)                              \
            _Pragma("unroll")                                       \
            for (int bb = 0; bb < 4; ++bb)                          \
                accf[aa][bb] = __builtin_amdgcn_mfma_f32_16x16x32_bf16( \
                    av[aa], bv[bb], accf[aa][bb], 0, 0, 0);         \
        __builtin_amdgcn_s_setprio(0);                              \
    } while (0)

    const bf16_t *cA0, *cB0, *cA1, *cB1;
    SETPTRS(tis[0], tjs[0], cA0, cB0, cA1, cB1);
    STAGEP(cA0, cB0, cA1, cB1, 0, 0);        // tile0 stage0 -> buf0
    STAGEP(cA0, cB0, cA1, cB1, BK, 1);       // tile0 stage1 -> buf1

    float c4 = 0.f;
    int seen = 0;

    #pragma unroll
    for (int g = 0; g < 3; ++g) {
        if (g >= ntile) break;
        int has_next = (g + 1 < ntile);
        const bf16_t *nA0 = cA0, *nB0 = cB0, *nA1 = cA1, *nB1 = cB1;
        if (has_next) SETPTRS(tis[g + 1], tjs[g + 1], nA0, nB0, nA1, nB1);

        f32x4 accf[4][4];
        #pragma unroll
        for (int a = 0; a < 4; ++a)
            #pragma unroll
            for (int bb = 0; bb < 4; ++bb)
                accf[a][bb] = (f32x4){0.f, 0.f, 0.f, 0.f};

        int rb = g % 3;
        const bf16_t *pA0 = cA0 + 2 * BK, *pB0 = cB0 + 2 * BK;
        const bf16_t *pA1 = cA1 + 2 * BK, *pB1 = cB1 + 2 * BK;
        for (int s = 0; s < 14; ++s) {
            WAITBAR("4");
            int wb = rb + 2; if (wb >= 3) wb -= 3;
            STAGEP(pA0, pB0, pA1, pB1, 0, wb);
            pA0 += BK; pB0 += BK; pA1 += BK; pB1 += BK;
            DOMFMA(rb);
            ++rb; if (rb == 3) rb = 0;
        }
        {   // step 14: read (g+2)%3; stage next tile's stage0 -> (g+1)%3
            WAITBAR("4");
            if (has_next) STAGEP(nA0, nB0, nA1, nB1, 0, (g + 1) % 3);
            DOMFMA((g + 2) % 3);
        }
        {   // step 15: read g%3; stage next tile's stage1 -> (g+2)%3
            if (has_next) {
                WAITBAR("4");
                STAGEP(nA0, nB0, nA1, nB1, BK, (g + 2) % 3);
            } else {
                WAITBAR("0");
            }
            DOMFMA(g % 3);
        }

        // epilogue: one-shot cvals sync, then 5-bandwidth RBF squaring chain
        if (!seen) {
            if (t == 0) {
                while (atomicAdd(flag, 0u) == 0u) __builtin_amdgcn_s_sleep(8);
                lds_c4 = atomicAdd(&cvals[4], 0.f);
            }
            __syncthreads();
            c4 = lds_c4;
            seen = 1;
        }
        int i0 = tis[g] * BT + wr * 64;
        int j0 = tjs[g] * BT + wc * 64;
        float sqi[4][4], sqj[4];
        #pragma unroll
        for (int aa = 0; aa < 4; ++aa)
            #pragma unroll
            for (int r = 0; r < 4; ++r)
                sqi[aa][r] = sqrow[i0 + 16 * aa + q16 * 4 + r];
        #pragma unroll
        for (int bb = 0; bb < 4; ++bb)
            sqj[bb] = sqrow[j0 + 16 * bb + n16];

        float s_local = 0.f;
        #pragma unroll
        for (int aa = 0; aa < 4; ++aa) {
            #pragma unroll
            for (int bb = 0; bb < 4; ++bb) {
                #pragma unroll
                for (int r = 0; r < 4; ++r) {
                    float d2 = fmaf(-2.f, accf[aa][bb][r], sqi[aa][r] + sqj[bb]);
                    d2 = fmaxf(d2, 0.f);
                    float e4 = EXP2F(d2 * c4);
                    float e3 = e4 * e4;
                    float e2 = e3 * e3;
                    float e1 = e2 * e2;
                    float e0 = e1 * e1;
                    s_local += e4 + e3 + e2 + e1 + e0;
                }
            }
        }
        #pragma unroll
        for (int off = 32; off > 0; off >>= 1) s_local += __shfl_down(s_local, off);
        if (lane == 0) wsum[wv] = s_local;
        __syncthreads();   // prefetched next-tile stages long done by now
        if (t == 0) {
            float bs = wsum[0] + wsum[1] + wsum[2] + wsum[3];
            double si = (tis[g] < NT / 2) ? 1.0 : -1.0;
            double sj = (tjs[g] < NT / 2) ? 1.0 : -1.0;
            double w = si * sj * ((tis[g] == tjs[g]) ? 1.0 : 2.0);
            double oldv = atomicAdd(&acc[(b & 7) * 16], w * (double)bs);
            asm volatile("" :: "v"(oldv));
        }
        if (has_next) { cA0 = nA0; cB0 = nB0; cA1 = nA1; cB1 = nB1; }
    }

    // fence-free final ticket (all older VMEM incl. acc atomics retired)
    if (t == 0) {
        asm volatile("s_waitcnt vmcnt(0)" ::: "memory");
        unsigned old = atomicAdd(tk2, 1u);
        if (old == NPERS - 1) {
            double ssum = 0.0;
            #pragma unroll
            for (int i = 0; i < 8; ++i) ssum += atomicAdd(&acc[i * 16], 0.0);
            out[0] = (float)(ssum / ((double)NX * (double)NX));
        }
    }
#undef SETPTRS
#undef STAGEP
#undef WAITBAR
#undef DOMFMA
}

extern "C" void kernel_launch(void* const* d_in, const int* in_sizes, int n_in,
                              void* d_out, int out_size, void* d_ws, size_t ws_size,
                              hipStream_t stream) {
    const float* X = (const float*)d_in[0];
    const float* Y = (const float*)d_in[1];
    float* out = (float*)d_out;

    float*    sqrow  = (float*)d_ws;
    float*    colsum = sqrow + 8192;
    float*    cvals  = (float*)((char*)d_ws + 34816);
    unsigned* tk1    = (unsigned*)((char*)d_ws + 34840);
    unsigned* tk2    = (unsigned*)((char*)d_ws + 34844);
    double*   S1acc  = (double*)((char*)d_ws + 34848);
    unsigned* flag   = (unsigned*)((char*)d_ws + 34860);
    double*   acc    = (double*)((char*)d_ws + 34944);
    bf16_t*   Zh     = (bf16_t*)((char*)d_ws + 36864);

    k_prep<<<2048, 256, 0, stream>>>(X, Y, Zh, sqrow, colsum, tk1, tk2, S1acc, flag);
    k_pair<<<NPERS, 256, 0, stream>>>(Zh, sqrow, colsum, cvals, S1acc, tk1, flag,
                                      acc, tk2, out);
}